// Round 7
// baseline (21.986 us; speedup 1.0000x reference)
//
#include <hip/hip_runtime.h>
#include <cmath>

typedef float f32x4 __attribute__((ext_vector_type(4)));

#define IMG_W 512
#define NROWS 8192                 // 16 batches * 512 rows
#define WPB 4                      // waves per block
#define TPB (WPB * 64)             // 256 threads
#define ROWS_PER_WAVE 2
#define NBLOCKS (NROWS / (WPB * ROWS_PER_WAVE))   // 1024
#define NCELLS 16
#define CELL_QUOTA (NBLOCKS / NCELLS)             // 64
#define CELL_STRIDE 16             // u64 words -> 128 B between cell lines

struct WinW { float w[11]; };

// ws64: cell k at word k*16; root at word NCELLS*16.
// Cell word: bits[55:63] = arrival count (add 1<<55), bits[0:54] = biased sum.
// Root word: bits[60:63] = cell count    (add 1<<60), bits[0:59] = biased sum.
// Block contribution: qp = round(sb * 2^24) + 2^36 (strictly positive).
// All atomics RELAXED agent-scope; the packed word carries count+sum together,
// so no fences / release-acquire are needed (that was R5's 50us mistake).

__global__ __launch_bounds__(TPB) void ssim_fused(
    const float* __restrict__ img1, const float* __restrict__ img2,
    unsigned long long* __restrict__ ws64, float* __restrict__ out, WinW ww)
{
    const int tid  = threadIdx.x;
    const int lane = tid & 63;
    const int wv   = tid >> 6;
    const int row0 = (blockIdx.x * WPB + wv) * ROWS_PER_WAVE;  // wave owns 2 rows

    const float C1 = 1e-4f;        // (0.01*1)^2
    const float C2 = 9e-4f;        // (0.03*1)^2

    // hoist ALL loads for both rows (8 x b128, coalesced, no redundancy)
    f32x4 La0[ROWS_PER_WAVE], La1[ROWS_PER_WAVE];
    f32x4 Lb0[ROWS_PER_WAVE], Lb1[ROWS_PER_WAVE];
    #pragma unroll
    for (int r = 0; r < ROWS_PER_WAVE; ++r) {
        const long long base = (long long)(row0 + r) * IMG_W + lane * 8;
        La0[r] = *(const f32x4*)&img1[base];
        La1[r] = *(const f32x4*)&img1[base + 4];
        Lb0[r] = *(const f32x4*)&img2[base];
        Lb1[r] = *(const f32x4*)&img2[base + 4];
    }

    float acc = 0.f;
    #pragma unroll
    for (int r = 0; r < ROWS_PER_WAVE; ++r) {
        // window W[j] = image col (8*lane - 5 + j), j = 0..17
        float W1[18], W2[18];
        #pragma unroll
        for (int j = 0; j < 4; ++j) {
            W1[5 + j] = La0[r][j];  W1[9 + j] = La1[r][j];
            W2[5 + j] = Lb0[r][j];  W2[9 + j] = Lb1[r][j];
        }
        // halo via neighbor lanes; lane-0/63 masks ARE the zero padding
        #pragma unroll
        for (int j = 0; j < 5; ++j) {
            const float u1 = __shfl_up(W1[8 + j], 1, 64);
            const float u2 = __shfl_up(W2[8 + j], 1, 64);
            W1[j] = (lane == 0) ? 0.f : u1;
            W2[j] = (lane == 0) ? 0.f : u2;
            const float d1 = __shfl_down(W1[5 + j], 1, 64);
            const float d2 = __shfl_down(W2[5 + j], 1, 64);
            W1[13 + j] = (lane == 63) ? 0.f : d1;
            W2[13 + j] = (lane == 63) ? 0.f : d2;
        }

        float AA[18], BB[18], AB[18];
        #pragma unroll
        for (int j = 0; j < 18; ++j) {
            AA[j] = W1[j] * W1[j];
            BB[j] = W2[j] * W2[j];
            AB[j] = W1[j] * W2[j];
        }

        #pragma unroll
        for (int p = 0; p < 8; ++p) {
            float mu1 = 0.f, mu2 = 0.f, s11 = 0.f, s22 = 0.f, s12 = 0.f;
            #pragma unroll
            for (int k = 0; k < 11; ++k) {
                const float wk = ww.w[k];
                mu1 = fmaf(wk, W1[p + k], mu1);
                mu2 = fmaf(wk, W2[p + k], mu2);
                s11 = fmaf(wk, AA[p + k], s11);
                s22 = fmaf(wk, BB[p + k], s22);
                s12 = fmaf(wk, AB[p + k], s12);
            }
            const float m12 = mu1 * mu2;
            const float m1s = mu1 * mu1;
            const float m2s = mu2 * mu2;
            const float num = (2.f * m12 + C1) * (2.f * (s12 - m12) + C2);
            const float den = (m1s + m2s + C1) * ((s11 - m1s) + (s22 - m2s) + C2);
            acc += num * __builtin_amdgcn_rcpf(den);   // ~1ulp vs 1.9e-2 thr
        }
    }

    // per-wave reduce, then one barrier for the block sum
    #pragma unroll
    for (int off = 32; off > 0; off >>= 1)
        acc += __shfl_down(acc, off, 64);
    __shared__ float wsum[WPB];
    if (lane == 0) wsum[wv] = acc;
    __syncthreads();

    if (tid == 0) {
        const float sb = wsum[0] + wsum[1] + wsum[2] + wsum[3];
        const double v = (double)sb * 16777216.0 + 68719476736.0 /*2^36 bias*/;
        const unsigned long long qp = (unsigned long long)(v + 0.5);

        unsigned long long* cell = ws64 + (blockIdx.x & (NCELLS - 1)) * CELL_STRIDE;
        const unsigned long long cadd = qp + (1ULL << 55);
        const unsigned long long cprev =
            __hip_atomic_fetch_add(cell, cadd, __ATOMIC_RELAXED,
                                   __HIP_MEMORY_SCOPE_AGENT);
        if ((cprev >> 55) == CELL_QUOTA - 1) {     // completed this cell
            const unsigned long long csum = (cprev + cadd) & ((1ULL << 55) - 1);
            const unsigned long long radd = csum + (1ULL << 60);
            const unsigned long long rprev =
                __hip_atomic_fetch_add(ws64 + NCELLS * CELL_STRIDE, radd,
                                       __ATOMIC_RELAXED,
                                       __HIP_MEMORY_SCOPE_AGENT);
            if ((rprev >> 60) == NCELLS - 1) {     // all cells in: finalize
                const unsigned long long rsum = (rprev + radd) & ((1ULL << 60) - 1);
                const long long q = (long long)rsum - ((long long)NBLOCKS << 36);
                const double total = (double)q / 16777216.0;
                // 10 fully zero-padded H rows per image have ssim == 1 exactly:
                // 16 * 10 * 512 = 81920 ones; mean over 16*522*512 = 4276224.
                out[0] = (float)(1.0 - (total + 81920.0) / 4276224.0);
            }
        }
    }
}

extern "C" void kernel_launch(void* const* d_in, const int* in_sizes, int n_in,
                              void* d_out, int out_size, void* d_ws, size_t ws_size,
                              hipStream_t stream) {
    const float* img1 = (const float*)d_in[0];
    const float* img2 = (const float*)d_in[1];
    float* out = (float*)d_out;
    unsigned long long* ws64 = (unsigned long long*)d_ws;

    // re-zero cells + root every call (d_ws is poisoned to 0xAA once)
    hipMemsetAsync(d_ws, 0, (NCELLS * CELL_STRIDE + 1) * 8, stream);

    // Gaussian window exactly like the reference:
    // exp in double -> cast f32, f32 sum, f32 divide.
    WinW ww;
    for (int i = 0; i < 11; ++i) {
        const double d = (double)(i - 5);
        ww.w[i] = (float)std::exp(-(d * d) / 4.5);
    }
    float s = 0.f;
    for (int i = 0; i < 11; ++i) s += ww.w[i];
    for (int i = 0; i < 11; ++i) ww.w[i] /= s;

    ssim_fused<<<NBLOCKS, TPB, 0, stream>>>(img1, img2, ws64, out, ww);
}

// Round 9
// 14.330 us; speedup vs baseline: 1.5342x; 1.5342x over previous
//
#include <hip/hip_runtime.h>
#include <cmath>

typedef float f32x2 __attribute__((ext_vector_type(2)));
typedef float f32x4 __attribute__((ext_vector_type(4)));

#define IMG_W 512
#define NROWS 8192                 // 16 batches * 512 rows
#define NBLOCKS (NROWS / 2)        // 4096: one row-PAIR per block
#define TPB 128                    // 4 columns per thread, 2 waves
#define FTPB 256                   // finalize block size

struct WinW { float w[11]; };

// k1: one row-pair per block, packed f32x2 {rowEven, rowOdd} lanes.
// 4 convs per pixel (mu1, mu2, conv(x1*x2), conv(x1^2+x2^2)) -- the
// denominator only needs sigma1^2+sigma2^2, so x1^2+x2^2 is ONE signal.
__global__ __launch_bounds__(TPB) void ssim_rows(
    const float* __restrict__ img1, const float* __restrict__ img2,
    float* __restrict__ partial, WinW ww)
{
    __shared__ __align__(16) f32x2 l1[528];
    __shared__ __align__(16) f32x2 l2[528];
    const int tid = threadIdx.x;
    const int col = 4 * tid;

    const float C1 = 1e-4f;        // (0.01*1)^2
    const float C2 = 9e-4f;        // (0.03*1)^2

    const long long r0 = (long long)blockIdx.x * 2 * IMG_W;   // even row base

    // coalesced 16B/lane loads: both rows, both images
    const f32x4 a0 = *(const f32x4*)&img1[r0 + col];
    const f32x4 a1 = *(const f32x4*)&img1[r0 + IMG_W + col];
    const f32x4 b0 = *(const f32x4*)&img2[r0 + col];
    const f32x4 b1 = *(const f32x4*)&img2[r0 + IMG_W + col];

    #pragma unroll
    for (int c = 0; c < 4; ++c) {
        l1[5 + col + c] = f32x2{a0[c], a1[c]};
        l2[5 + col + c] = f32x2{b0[c], b1[c]};
    }
    if (tid < 16) {                // halo: idx 0..4 and 517..527 -> zero
        const int slot = (tid < 5) ? tid : (512 + tid);
        l1[slot] = f32x2{0.f, 0.f};
        l2[slot] = f32x2{0.f, 0.f};
    }
    __syncthreads();               // single barrier; no LDS reuse

    // pixels col..col+3 need lds idx col..col+13 (read 16, b128-aligned)
    f32x2 a[16], b[16];
    #pragma unroll
    for (int s = 0; s < 8; ++s) {
        *(f32x4*)&a[2 * s] = *(const f32x4*)&l1[col + 2 * s];
        *(f32x4*)&b[2 * s] = *(const f32x4*)&l2[col + 2 * s];
    }

    f32x2 mu1[4], mu2[4], sab[4], sqq[4];
    #pragma unroll
    for (int p = 0; p < 4; ++p) {
        mu1[p] = f32x2{0.f, 0.f}; mu2[p] = f32x2{0.f, 0.f};
        sab[p] = f32x2{0.f, 0.f}; sqq[p] = f32x2{0.f, 0.f};
    }

    // per-column products once (qq = a^2+b^2, ab = a*b), consumed by <=4 pixels
    #pragma unroll
    for (int j = 0; j < 14; ++j) {
        const f32x2 aj = a[j], bj = b[j];
        const f32x2 qq = aj * aj + bj * bj;
        const f32x2 ab = aj * bj;
        #pragma unroll
        for (int p = 0; p < 4; ++p) {
            const int k = j - p;
            if (k >= 0 && k < 11) {
                const float wk = ww.w[k];
                mu1[p] += wk * aj;
                mu2[p] += wk * bj;
                sab[p] += wk * ab;
                sqq[p] += wk * qq;
            }
        }
    }

    f32x2 acc = {0.f, 0.f};
    #pragma unroll
    for (int p = 0; p < 4; ++p) {
        const f32x2 m12  = mu1[p] * mu2[p];
        const f32x2 msum = mu1[p] * mu1[p] + mu2[p] * mu2[p];
        const f32x2 num  = (2.f * m12 + C1) * (2.f * (sab[p] - m12) + C2);
        const f32x2 den  = (msum + C1) * ((sqq[p] - msum) + C2);
        f32x2 r;
        r.x = __builtin_amdgcn_rcpf(den.x);   // ~1ulp vs 1.9e-2 threshold
        r.y = __builtin_amdgcn_rcpf(den.y);
        acc += num * r;
    }

    float s = acc.x + acc.y;
    #pragma unroll
    for (int off = 32; off > 0; off >>= 1)
        s += __shfl_down(s, off, 64);
    __shared__ float wsum[TPB / 64];
    if ((tid & 63) == 0) wsum[tid >> 6] = s;
    __syncthreads();
    if (tid == 0) partial[blockIdx.x] = wsum[0] + wsum[1];
}

__global__ __launch_bounds__(FTPB) void ssim_final(
    const float* __restrict__ partial, float* __restrict__ out)
{
    const int tid = threadIdx.x;
    float s = 0.f;
    #pragma unroll
    for (int i = 0; i < NBLOCKS / (FTPB * 4); ++i) {       // 4 x float4 each
        const f32x4 v = *(const f32x4*)&partial[4 * (tid + FTPB * i)];
        s += (v[0] + v[1]) + (v[2] + v[3]);
    }
    #pragma unroll
    for (int off = 32; off > 0; off >>= 1)
        s += __shfl_down(s, off, 64);
    __shared__ float ws[FTPB / 64];
    if ((tid & 63) == 0) ws[tid >> 6] = s;
    __syncthreads();
    if (tid == 0) {
        const float total = ws[0] + ws[1] + ws[2] + ws[3];
        // 10 fully zero-padded H rows per image have ssim == 1 exactly:
        // 16 * 10 * 512 = 81920 ones; mean over 16*522*512 = 4276224.
        out[0] = 1.0f - (total + 81920.0f) / 4276224.0f;
    }
}

extern "C" void kernel_launch(void* const* d_in, const int* in_sizes, int n_in,
                              void* d_out, int out_size, void* d_ws, size_t ws_size,
                              hipStream_t stream) {
    const float* img1 = (const float*)d_in[0];
    const float* img2 = (const float*)d_in[1];
    float* out = (float*)d_out;
    float* partial = (float*)d_ws;   // 4096 floats, fully overwritten each call

    // Gaussian window exactly like the reference:
    // exp in double -> cast f32, f32 sum, f32 divide.
    WinW ww;
    for (int i = 0; i < 11; ++i) {
        const double d = (double)(i - 5);
        ww.w[i] = (float)std::exp(-(d * d) / 4.5);
    }
    float s = 0.f;
    for (int i = 0; i < 11; ++i) s += ww.w[i];
    for (int i = 0; i < 11; ++i) ww.w[i] /= s;

    ssim_rows<<<NBLOCKS, TPB, 0, stream>>>(img1, img2, partial, ww);
    ssim_final<<<1, FTPB, 0, stream>>>(partial, out);
}